// Round 10
// baseline (644.658 us; speedup 1.0000x reference)
//
#include <hip/hip_runtime.h>

// ---------------------------------------------------------------------------
// CausalLinearAttention (B=4, T=4096, D=1024, H=16, dk=dv=64, CHUNK=64)
// Round 10: fused QKV GEMM -- one 768-WG launch over wcat=[Wq;Wk;Wv], with
// PROVEN lane-major epilogues (R4 lesson): Q/K natural; V via operand-swap
// (mfma(w,x) -> D[wrow][token]) + same contiguous scalar stores into vT.
// Mapping: rep=bid>>8 (Q/K/V), s=XCDswz(bid&255) -> (tm, tnl); a CU's 3
// sequential WGs share tm -> A-panel L2 reuse.  Rest = R9 best-known.
// ---------------------------------------------------------------------------

typedef unsigned short u16;
typedef float  f32x4 __attribute__((ext_vector_type(4)));
typedef short  b16x8 __attribute__((ext_vector_type(8)));
typedef u16    u16x4 __attribute__((ext_vector_type(4)));
typedef u16    u16x8 __attribute__((ext_vector_type(8)));

#define DEVINL __device__ __forceinline__

DEVINL u16 f2b(float f) {           // f32 -> bf16 RNE
  unsigned u = __float_as_uint(f);
  return (u16)((u + 0x7fffu + ((u >> 16) & 1u)) >> 16);
}
DEVINL float b2f(u16 s) { return __uint_as_float(((unsigned)s) << 16); }

DEVINL f32x4 mfma16(b16x8 a, b16x8 b, f32x4 c) {
  return __builtin_amdgcn_mfma_f32_16x16x32_bf16(a, b, c, 0, 0, 0);
}

DEVINL float phi_elu1(float v) { return v > 0.f ? v + 1.f : __expf(v); }

// ---------------------------------------------------------------- cvt f32->bf16
__global__ void cvt_kernel(const float* __restrict__ in, u16* __restrict__ out, int n8) {
  int stride = gridDim.x * blockDim.x;
  for (int i = blockIdx.x * blockDim.x + threadIdx.x; i < n8; i += stride) {
    const float* p = in + (size_t)i * 8;
    f32x4 a = *(const f32x4*)p;
    f32x4 b = *(const f32x4*)(p + 4);
    u16x8 o;
    o[0] = f2b(a[0]); o[1] = f2b(a[1]); o[2] = f2b(a[2]); o[3] = f2b(a[3]);
    o[4] = f2b(b[0]); o[5] = f2b(b[1]); o[6] = f2b(b[2]); o[7] = f2b(b[3]);
    *(u16x8*)(out + (size_t)i * 8) = o;
  }
}

__global__ void cvt4_kernel(const float* __restrict__ p0, const float* __restrict__ p1,
                            const float* __restrict__ p2, const float* __restrict__ p3,
                            u16* __restrict__ o0, u16* __restrict__ o1,
                            u16* __restrict__ o2, u16* __restrict__ o3) {
  const float* in; u16* out;
  switch (blockIdx.y) {
    case 0: in = p0; out = o0; break;
    case 1: in = p1; out = o1; break;
    case 2: in = p2; out = o2; break;
    default: in = p3; out = o3; break;
  }
  int i = blockIdx.x * blockDim.x + threadIdx.x;
  const float* p = in + (size_t)i * 8;
  f32x4 a = *(const f32x4*)p;
  f32x4 b = *(const f32x4*)(p + 4);
  u16x8 o;
  o[0] = f2b(a[0]); o[1] = f2b(a[1]); o[2] = f2b(a[2]); o[3] = f2b(a[3]);
  o[4] = f2b(b[0]); o[5] = f2b(b[1]); o[6] = f2b(b[2]); o[7] = f2b(b[3]);
  *(u16x8*)(out + (size_t)i * 8) = o;
}

#define STAGE(tt, h)                                                            \
  do {                                                                          \
    const u16* s_ = ((h) < 2 ? sA : sB) + (size_t)(((h) & 1) * 128) * 1024 +    \
                    (size_t)(tt) * 64;                                          \
    char* d_ = ldsStage + (((tt) & 1) << 16) + ((h) < 2 ? 0 : 32768) +          \
               (((h) & 1) << 14);                                               \
    __builtin_amdgcn_global_load_lds(                                           \
        (const __attribute__((address_space(1))) void*)(s_),                    \
        (__attribute__((address_space(3))) void*)(d_), 16, 0, 0);               \
    __builtin_amdgcn_global_load_lds(                                           \
        (const __attribute__((address_space(1))) void*)(s_ + 64 * 1024),        \
        (__attribute__((address_space(3))) void*)(d_ + 8192), 16, 0, 0);        \
  } while (0)

#define BAR_SB()                                                                \
  do {                                                                          \
    __builtin_amdgcn_s_barrier();                                               \
    __builtin_amdgcn_sched_barrier(0);                                          \
  } while (0)

// ------------------------------- fused QKV GEMM, 2 barriers/K-tile, grid 768
// rep = bid>>8: 0->phiQ, 1->phiK, 2->vT.  s = XCD-swizzle(bid&255);
// tm = s>>2 (token tile), tnl = s&3 (256-col block of this output).
// Q/K: acc = mfma(x_frag, w_frag) -> D[token][wcol], natural stores + PHI.
// V:   acc = mfma(w_frag, x_frag) -> D[wrow][token], stores into vT rows
//      (l15-contiguous tokens -- proven store contiguity class).
__global__ __launch_bounds__(512, 2) void gemm256qkv(const u16* __restrict__ A,
                                                     const u16* __restrict__ W,
                                                     u16* __restrict__ phiQ,
                                                     u16* __restrict__ phiK,
                                                     u16* __restrict__ vT) {
  __shared__ char lds[131072];
  const int tid = threadIdx.x, wid = tid >> 6, l = tid & 63;
  const int l15 = l & 15, lg = l >> 4;
  const int wr = wid >> 2, wc = wid & 3;
  const int bid = blockIdx.x;
  const int g = bid & 255, rep = bid >> 8;
  const int s = (g & 7) * 32 + (g >> 3);            // XCD swizzle (bijective)
  const int tm = s >> 2, tnl = s & 3;
  const bool isV = (rep == 2);

  const int colX0 = (lg * 16) ^ ((l15 & 7) << 4);
  const int colX1 = (64 + lg * 16) ^ ((l15 & 7) << 4);
  char* ldsA = lds + wr * 16384 + l15 * 128;
  char* ldsB = lds + 32768 + (wc >> 1) * 16384 + ((wc & 1) * 64 + l15) * 128;
  const int srow = tid >> 3;
  const int scol = ((((tid & 7) * 16) ^ ((srow & 7) << 4)) >> 1);
  const u16* sA = A + (size_t)(tm * 256 + srow) * 1024 + scol;
  const u16* sB = W + (size_t)((rep * 4 + tnl) * 256 + srow) * 1024 + scol;
  char* ldsStage = lds + wid * 1024;

  f32x4 acc[8][4];
#pragma unroll
  for (int i = 0; i < 8; i++)
#pragma unroll
    for (int j = 0; j < 4; j++) acc[i][j] = f32x4{0.f, 0.f, 0.f, 0.f};

  STAGE(0, 0); STAGE(0, 1); STAGE(0, 2); STAGE(0, 3);
  STAGE(1, 2); STAGE(1, 3);
  asm volatile("s_waitcnt vmcnt(4)" ::: "memory");

  b16x8 a0[4], a1[4], b0[4], b1[4];
  for (int t = 0; t < 16; ++t) {
    const int cb = (t & 1) << 16;
    // ---- phase A (ks0)
    BAR_SB();
#pragma unroll
    for (int fm = 0; fm < 4; fm++) {
      a0[fm] = *(const b16x8*)(ldsA + cb + fm * 2048 + colX0);
      a1[fm] = *(const b16x8*)(ldsA + cb + (4 + fm) * 2048 + colX0);
    }
#pragma unroll
    for (int fn = 0; fn < 4; fn++) b0[fn] = *(const b16x8*)(ldsB + cb + fn * 2048 + colX0);
    if (t < 15) { STAGE(t + 1, 0); STAGE(t + 1, 1); }
    __builtin_amdgcn_s_setprio(1);
    if (!isV) {
#pragma unroll
      for (int fm = 0; fm < 4; fm++)
#pragma unroll
        for (int fn = 0; fn < 4; fn++) {
          acc[fm][fn] = mfma16(a0[fm], b0[fn], acc[fm][fn]);
          acc[4 + fm][fn] = mfma16(a1[fm], b0[fn], acc[4 + fm][fn]);
        }
    } else {
#pragma unroll
      for (int fm = 0; fm < 4; fm++)
#pragma unroll
        for (int fn = 0; fn < 4; fn++) {
          acc[fm][fn] = mfma16(b0[fn], a0[fm], acc[fm][fn]);
          acc[4 + fm][fn] = mfma16(b0[fn], a1[fm], acc[4 + fm][fn]);
        }
    }
    __builtin_amdgcn_s_setprio(0);
    // ---- phase B (ks1)
    BAR_SB();
#pragma unroll
    for (int fm = 0; fm < 4; fm++) {
      a0[fm] = *(const b16x8*)(ldsA + cb + fm * 2048 + colX1);
      a1[fm] = *(const b16x8*)(ldsA + cb + (4 + fm) * 2048 + colX1);
    }
#pragma unroll
    for (int fn = 0; fn < 4; fn++) b1[fn] = *(const b16x8*)(ldsB + cb + fn * 2048 + colX1);
    if (t < 14) { STAGE(t + 2, 2); STAGE(t + 2, 3); }
    __builtin_amdgcn_s_setprio(1);
    if (!isV) {
#pragma unroll
      for (int fm = 0; fm < 4; fm++)
#pragma unroll
        for (int fn = 0; fn < 4; fn++) {
          acc[fm][fn] = mfma16(a0[fm], b1[fn], acc[fm][fn]);
          acc[4 + fm][fn] = mfma16(a1[fm], b1[fn], acc[4 + fm][fn]);
        }
    } else {
#pragma unroll
      for (int fm = 0; fm < 4; fm++)
#pragma unroll
        for (int fn = 0; fn < 4; fn++) {
          acc[fm][fn] = mfma16(b1[fn], a0[fm], acc[fm][fn]);
          acc[4 + fm][fn] = mfma16(b1[fn], a1[fm], acc[4 + fm][fn]);
        }
    }
    __builtin_amdgcn_s_setprio(0);
    if (t < 14) asm volatile("s_waitcnt vmcnt(4)" ::: "memory");
    else        asm volatile("s_waitcnt vmcnt(0)" ::: "memory");
  }

  if (!isV) {
    u16* Cc = (rep == 0) ? phiQ : phiK;
#pragma unroll
    for (int fm = 0; fm < 8; ++fm)
#pragma unroll
      for (int fn = 0; fn < 4; ++fn)
#pragma unroll
        for (int r = 0; r < 4; ++r) {
          size_t grow = (size_t)tm * 256 + wr * 128 + fm * 16 + lg * 4 + r;
          size_t gcol = (size_t)tnl * 256 + wc * 64 + fn * 16 + l15;
          Cc[grow * 1024 + gcol] = f2b(phi_elu1(acc[fm][fn][r]));
        }
  } else {
    // D[wrow][token]: wrow from (fn,lg,r) in the B wave-tile, token l15-contig.
#pragma unroll
    for (int fm = 0; fm < 8; ++fm)
#pragma unroll
      for (int fn = 0; fn < 4; ++fn)
#pragma unroll
        for (int r = 0; r < 4; ++r) {
          size_t vrow = (size_t)tnl * 256 + wc * 64 + fn * 16 + lg * 4 + r;
          size_t tok = (size_t)tm * 256 + wr * 128 + fm * 16 + l15;
          vT[vrow * 16384 + tok] = f2b(acc[fm][fn][r]);
        }
  }
}

// -------------------------------------- 256^2 GEMM, 2 barriers per K-tile
template <bool PHI, typename OT>
__global__ __launch_bounds__(512, 2) void gemm256g(const u16* __restrict__ A,
                                                   const u16* __restrict__ B,
                                                   OT* __restrict__ C, int M, int N) {
  __shared__ char lds[131072];
  const int tid = threadIdx.x, wid = tid >> 6, l = tid & 63;
  const int l15 = l & 15, lg = l >> 4;
  const int wr = wid >> 2, wc = wid & 3;
  const int ntn = N >> 8;
  const int nwg = gridDim.x, bid = blockIdx.x;
  const int cpx = nwg >> 3;
  const int sb = (bid & 7) * cpx + (bid >> 3);
  const int tm = sb / ntn, tn = sb - tm * ntn;
  const int colX0 = (lg * 16) ^ ((l15 & 7) << 4);
  const int colX1 = (64 + lg * 16) ^ ((l15 & 7) << 4);
  char* ldsA = lds + wr * 16384 + l15 * 128;
  char* ldsB = lds + 32768 + (wc >> 1) * 16384 + ((wc & 1) * 64 + l15) * 128;
  const int srow = tid >> 3;
  const int scol = ((((tid & 7) * 16) ^ ((srow & 7) << 4)) >> 1);
  const u16* sA = A + (size_t)(tm * 256 + srow) * 1024 + scol;
  const u16* sB = B + (size_t)(tn * 256 + srow) * 1024 + scol;
  char* ldsStage = lds + wid * 1024;

  f32x4 acc[8][4];
#pragma unroll
  for (int i = 0; i < 8; i++)
#pragma unroll
    for (int j = 0; j < 4; j++) acc[i][j] = f32x4{0.f, 0.f, 0.f, 0.f};

  STAGE(0, 0); STAGE(0, 1); STAGE(0, 2); STAGE(0, 3);
  STAGE(1, 2); STAGE(1, 3);
  asm volatile("s_waitcnt vmcnt(4)" ::: "memory");

  b16x8 a0[4], a1[4], b0[4], b1[4];
  for (int t = 0; t < 16; ++t) {
    const int cb = (t & 1) << 16;
    BAR_SB();
#pragma unroll
    for (int fm = 0; fm < 4; fm++) {
      a0[fm] = *(const b16x8*)(ldsA + cb + fm * 2048 + colX0);
      a1[fm] = *(const b16x8*)(ldsA + cb + (4 + fm) * 2048 + colX0);
    }
#pragma unroll
    for (int fn = 0; fn < 4; fn++) b0[fn] = *(const b16x8*)(ldsB + cb + fn * 2048 + colX0);
    if (t < 15) { STAGE(t + 1, 0); STAGE(t + 1, 1); }
    __builtin_amdgcn_s_setprio(1);
#pragma unroll
    for (int fm = 0; fm < 4; fm++)
#pragma unroll
      for (int fn = 0; fn < 4; fn++) {
        acc[fm][fn] = mfma16(a0[fm], b0[fn], acc[fm][fn]);
        acc[4 + fm][fn] = mfma16(a1[fm], b0[fn], acc[4 + fm][fn]);
      }
    __builtin_amdgcn_s_setprio(0);
    BAR_SB();
#pragma unroll
    for (int fm = 0; fm < 4; fm++) {
      a0[fm] = *(const b16x8*)(ldsA + cb + fm * 2048 + colX1);
      a1[fm] = *(const b16x8*)(ldsA + cb + (4 + fm) * 2048 + colX1);
    }
#pragma unroll
    for (int fn = 0; fn < 4; fn++) b1[fn] = *(const b16x8*)(ldsB + cb + fn * 2048 + colX1);
    if (t < 14) { STAGE(t + 2, 2); STAGE(t + 2, 3); }
    __builtin_amdgcn_s_setprio(1);
#pragma unroll
    for (int fm = 0; fm < 4; fm++)
#pragma unroll
      for (int fn = 0; fn < 4; fn++) {
        acc[fm][fn] = mfma16(a0[fm], b1[fn], acc[fm][fn]);
        acc[4 + fm][fn] = mfma16(a1[fm], b1[fn], acc[4 + fm][fn]);
      }
    __builtin_amdgcn_s_setprio(0);
    if (t < 14) asm volatile("s_waitcnt vmcnt(4)" ::: "memory");
    else        asm volatile("s_waitcnt vmcnt(0)" ::: "memory");
  }

#pragma unroll
  for (int fm = 0; fm < 8; ++fm)
#pragma unroll
    for (int fn = 0; fn < 4; ++fn)
#pragma unroll
      for (int r = 0; r < 4; ++r) {
        size_t grow = (size_t)tm * 256 + wr * 128 + fm * 16 + lg * 4 + r;
        size_t gcol = (size_t)tn * 256 + wc * 64 + fn * 16 + l15;
        float v = acc[fm][fn][r];
        if (PHI) v = phi_elu1(v);
        OT* p = C + grow * (size_t)N + gcol;
        if constexpr (sizeof(OT) == 2) *p = (OT)f2b(v);
        else                           *p = (OT)v;
      }
}

// ------------------- per-chunk KV^T (=v^T k) and Ksum, fused phiK transpose
__global__ __launch_bounds__(256, 2) void kv_kernel(const u16* __restrict__ phiK,
                                                    const u16* __restrict__ vT,
                                                    u16* __restrict__ KVT,
                                                    float* __restrict__ Ksum) {
  __shared__ u16 tile[4][64][68];                   // per-wave, +4 pad
  const int tid = threadIdx.x, wid = tid >> 6, l = tid & 63, l15 = l & 15, lg = l >> 4;
  const int bid = blockIdx.x, hg = bid & 3, bn = bid >> 2, n = bn & 63, b = bn >> 6;
  const int h = hg * 4 + wid;
  const size_t row0 = (size_t)b * 4096 + n * 64;
  const int dcol = h * 64;
  const size_t cb = (size_t)b * 4096 + n * 64 + lg * 8;

  b16x8 af[4][2];
#pragma unroll
  for (int fm = 0; fm < 4; fm++)
#pragma unroll
    for (int ks = 0; ks < 2; ks++)
      af[fm][ks] = *(const b16x8*)(vT + (size_t)(h * 64 + fm * 16 + l15) * 16384 + cb + ks * 32);

  u16 (*tw)[68] = tile[wid];
#pragma unroll
  for (int i = 0; i < 8; i++) {
    int tok = i * 8 + (l >> 3);
    int c8 = (l & 7) * 8;
    u16x8 v = *(const u16x8*)(phiK + (row0 + tok) * 1024 + dcol + c8);
    *(u16x4*)(&tw[tok][c8]) = u16x4{v[0], v[1], v[2], v[3]};
    *(u16x4*)(&tw[tok][c8 + 4]) = u16x4{v[4], v[5], v[6], v[7]};
  }
  __syncthreads();

  b16x8 bf[4][2];
#pragma unroll
  for (int fn = 0; fn < 4; fn++)
#pragma unroll
    for (int ks = 0; ks < 2; ks++) {
      b16x8 t;
#pragma unroll
      for (int j = 0; j < 8; j++)
        t[j] = (short)tw[lg * 8 + ks * 32 + j][fn * 16 + l15];
      bf[fn][ks] = t;
    }

  f32x4 acc[4][4];
#pragma unroll
  for (int i = 0; i < 4; i++)
#pragma unroll
    for (int j = 0; j < 4; j++) acc[i][j] = f32x4{0.f, 0.f, 0.f, 0.f};
#pragma unroll
  for (int ks = 0; ks < 2; ks++)
#pragma unroll
    for (int fm = 0; fm < 4; fm++)
#pragma unroll
      for (int fn = 0; fn < 4; fn++) acc[fm][fn] = mfma16(af[fm][ks], bf[fn][ks], acc[fm][fn]);

  float ksum[4] = {0.f, 0.f, 0.f, 0.f};
#pragma unroll
  for (int fn = 0; fn < 4; fn++) {
#pragma unroll
    for (int ks = 0; ks < 2; ks++)
#pragma unroll
      for (int j = 0; j < 8; j++) ksum[fn] += b2f((u16)bf[fn][ks][j]);
    ksum[fn] += __shfl_xor(ksum[fn], 16);
    ksum[fn] += __shfl_xor(ksum[fn], 32);
  }
  const size_t ob = (size_t)(b * 16 + h) * 64 + n;
  if (l < 16) {
#pragma unroll
    for (int fn = 0; fn < 4; fn++) Ksum[ob * 64 + fn * 16 + l15] = ksum[fn];
  }
#pragma unroll
  for (int fm = 0; fm < 4; fm++)
#pragma unroll
    for (int fn = 0; fn < 4; fn++)
#pragma unroll
      for (int r = 0; r < 4; r++)
        KVT[ob * 4096 + (size_t)(fm * 16 + lg * 4 + r) * 64 + fn * 16 + l15] =
            f2b(acc[fm][fn][r]);
}

// ----------------------------- exclusive prefix scans (S and z in one launch)
__global__ __launch_bounds__(256) void scan_s(const u16* __restrict__ KVT,
                                              u16* __restrict__ ST,
                                              const float* __restrict__ Ksum,
                                              float* __restrict__ zpre) {
  if (blockIdx.x >= 1024) {
    const int gi = (blockIdx.x - 1024) * 256 + threadIdx.x;
    const size_t bh = gi >> 6;
    const int dk = gi & 63;
    float acc = 0.f;
    for (int n = 0; n < 64; n++) {
      size_t idx = (bh * 64 + n) * 64 + dk;
      zpre[idx] = acc;
      acc += Ksum[idx];
    }
    return;
  }
  const size_t base = (size_t)(blockIdx.x >> 4) * 64 * 4096 +
                      (blockIdx.x & 15) * 256 + threadIdx.x;
  float acc = 0.f;
  float v[4], w[4];
#pragma unroll
  for (int i = 0; i < 4; i++) v[i] = b2f(KVT[base + (size_t)i * 4096]);
  for (int n = 0; n < 64; n += 4) {
    if (n < 60) {
#pragma unroll
      for (int i = 0; i < 4; i++) w[i] = b2f(KVT[base + (size_t)(n + 4 + i) * 4096]);
    } else {
#pragma unroll
      for (int i = 0; i < 4; i++) w[i] = 0.f;
    }
#pragma unroll
    for (int i = 0; i < 4; i++) {
      ST[base + (size_t)(n + i) * 4096] = f2b(acc);
      acc += v[i];
    }
#pragma unroll
    for (int i = 0; i < 4; i++) v[i] = w[i];
  }
}

// -------------------------------------------------------- fused chunk attention
__global__ __launch_bounds__(256, 2) void attn_out(const u16* __restrict__ phiQ,
                                                   const u16* __restrict__ phiK,
                                                   const u16* __restrict__ vT,
                                                   const u16* __restrict__ ST,
                                                   const float* __restrict__ zpre,
                                                   u16* __restrict__ Y) {
  __shared__ char lds[4 * 8192 + 4 * 256];
  const int tid = threadIdx.x, wid = tid >> 6, l = tid & 63, l15 = l & 15, lg = l >> 4;
  const int bid = blockIdx.x, hg = bid & 3, bn = bid >> 2, n = bn & 63, b = bn >> 6;
  const int h = hg * 4 + wid;
  const size_t row0 = (size_t)b * 4096 + n * 64;
  const int dcol = h * 64;

  b16x8 qf[4][2];
#pragma unroll
  for (int fi = 0; fi < 4; fi++)
#pragma unroll
    for (int ks = 0; ks < 2; ks++)
      qf[fi][ks] = *(const b16x8*)(phiQ + (row0 + fi * 16 + l15) * 1024 + dcol + lg * 8 + ks * 32);

  f32x4 accT[4][4];
#pragma unroll
  for (int i = 0; i < 4; i++)
#pragma unroll
    for (int j = 0; j < 4; j++) accT[i][j] = f32x4{0.f, 0.f, 0.f, 0.f};
  {
    b16x8 kf[4][2];
#pragma unroll
    for (int fj = 0; fj < 4; fj++)
#pragma unroll
      for (int ks = 0; ks < 2; ks++)
        kf[fj][ks] = *(const b16x8*)(phiK + (row0 + fj * 16 + l15) * 1024 + dcol + lg * 8 + ks * 32);
#pragma unroll
    for (int ks = 0; ks < 2; ks++)
#pragma unroll
      for (int fj = 0; fj < 4; fj++)
#pragma unroll
        for (int fi = 0; fi < 4; fi++)
          accT[fj][fi] = mfma16(kf[fj][ks], qf[fi][ks], accT[fj][fi]);
  }

  const size_t zb = ((size_t)(b * 16 + h) * 64 + n) * 64;
  float zi[4] = {0.f, 0.f, 0.f, 0.f};
#pragma unroll
  for (int ks = 0; ks < 2; ks++) {
    f32x4 z0 = *(const f32x4*)(zpre + zb + lg * 8 + ks * 32);
    f32x4 z1 = *(const f32x4*)(zpre + zb + lg * 8 + ks * 32 + 4);
#pragma unroll
    for (int fi = 0; fi < 4; fi++)
#pragma unroll
      for (int j = 0; j < 4; j++) {
        zi[fi] += b2f((u16)qf[fi][ks][j])     * z0[j];
        zi[fi] += b2f((u16)qf[fi][ks][j + 4]) * z1[j];
      }
  }

  char* abuf = lds + wid * 8192;
  float zt[4] = {0.f, 0.f, 0.f, 0.f};
#pragma unroll
  for (int fi = 0; fi < 4; fi++) {
    const int i = fi * 16 + l15;
    const int swz = (i & 7) << 4;
#pragma unroll
    for (int fj = 0; fj < 4; fj++) {
      f32x4 v = accT[fj][fi];
#pragma unroll
      for (int r = 0; r < 4; r++) {
        int j = fj * 16 + lg * 4 + r;
        if (j > i) v[r] = 0.f;
        zt[fi] += v[r];
      }
      unsigned w0 = (unsigned)f2b(v[0]) | ((unsigned)f2b(v[1]) << 16);
      unsigned w1 = (unsigned)f2b(v[2]) | ((unsigned)f2b(v[3]) << 16);
      int jb = (fj * 16 + lg * 4) * 2;
      *(unsigned*)(abuf + i * 128 + (jb ^ swz)) = w0;
      *(unsigned*)(abuf + i * 128 + ((jb + 4) ^ swz)) = w1;
    }
  }

  float* dbuf = (float*)(lds + 32768 + wid * 256);
#pragma unroll
  for (int fi = 0; fi < 4; fi++) {
    float z = zi[fi] + zt[fi];
    z += __shfl_xor(z, 16);
    z += __shfl_xor(z, 32);
    float rd = 1.f / fmaxf(z, 1e-6f);
    if (l < 16) dbuf[fi * 16 + l15] = rd;
  }
  __syncthreads();

  b16x8 stf[4][2], vf[4][2];
  const size_t stb = ((size_t)(b * 16 + h) * 64 + n) * 4096;
#pragma unroll
  for (int fn = 0; fn < 4; fn++)
#pragma unroll
    for (int ks = 0; ks < 2; ks++) {
      stf[fn][ks] = *(const b16x8*)(ST + stb + (size_t)(fn * 16 + l15) * 64 + lg * 8 + ks * 32);
      vf[fn][ks]  = *(const b16x8*)(vT + (size_t)(dcol + fn * 16 + l15) * 16384 +
                                    (size_t)b * 4096 + n * 64 + lg * 8 + ks * 32);
    }
  f32x4 acc[4][4];
#pragma unroll
  for (int i = 0; i < 4; i++)
#pragma unroll
    for (int j = 0; j < 4; j++) acc[i][j] = f32x4{0.f, 0.f, 0.f, 0.f};
#pragma unroll
  for (int ks = 0; ks < 2; ks++)
#pragma unroll
    for (int fm = 0; fm < 4; fm++)
#pragma unroll
      for (int fn = 0; fn < 4; fn++) acc[fm][fn] = mfma16(qf[fm][ks], stf[fn][ks], acc[fm][fn]);
#pragma unroll
  for (int fm = 0; fm < 4; fm++) {
    const int i = fm * 16 + l15;
    const int swz = (i & 7) << 4;
#pragma unroll
    for (int ks = 0; ks < 2; ks++) {
      b16x8 af = *(const b16x8*)(abuf + i * 128 + ((ks * 64 + lg * 16) ^ swz));
#pragma unroll
      for (int fn = 0; fn < 4; fn++) acc[fm][fn] = mfma16(af, vf[fn][ks], acc[fm][fn]);
    }
  }

#pragma unroll
  for (int fm = 0; fm < 4; fm++)
#pragma unroll
    for (int r = 0; r < 4; r++) {
      float rd = dbuf[fm * 16 + lg * 4 + r];
#pragma unroll
      for (int fn = 0; fn < 4; fn++)
        Y[(row0 + fm * 16 + lg * 4 + r) * 1024 + dcol + fn * 16 + l15] =
            f2b(acc[fm][fn][r] * rd);
    }
}

// ---------------------------------------------------------------------------
extern "C" void kernel_launch(void* const* d_in, const int* in_sizes, int n_in,
                              void* d_out, int out_size, void* d_ws, size_t ws_size,
                              hipStream_t stream) {
  const float* x  = (const float*)d_in[0];
  const float* Wq = (const float*)d_in[1];
  const float* Wk = (const float*)d_in[2];
  const float* Wv = (const float*)d_in[3];
  const float* Wo = (const float*)d_in[4];
  float* out = (float*)d_out;

  char* ws = (char*)d_ws;
  size_t off = 0;
  auto alloc = [&](size_t bytes) -> char* {
    char* p = ws + off;
    off += (bytes + 255) & ~(size_t)255;
    return p;
  };
  u16*   xb   = (u16*)alloc(33554432);   // x bf16 (reused as y later)
  u16*   wcat = (u16*)alloc(6291456);    // [Wq;Wk;Wv] bf16 3072x1024
  u16*   wob  = (u16*)alloc(2097152);
  u16*   phiQ = (u16*)alloc(33554432);
  u16*   phiK = (u16*)alloc(33554432);
  u16*   vT   = (u16*)alloc(33554432);
  u16*   KVT  = (u16*)alloc(33554432);
  float* Ksum = (float*)alloc(1048576);
  u16*   ST   = (u16*)alloc(33554432);
  float* zpre = (float*)alloc(1048576);
  u16*   y    = xb;   // alias: xb dead after the QKV GEMM

  cvt_kernel<<<2048, 256, 0, stream>>>(x, xb, 2097152);
  cvt4_kernel<<<dim3(512, 4), 256, 0, stream>>>(
      Wq, Wk, Wv, Wo, wcat, wcat + 1048576, wcat + 2097152, wob);

  gemm256qkv<<<768, 512, 0, stream>>>(xb, wcat, phiQ, phiK, vT);

  kv_kernel<<<1024, 256, 0, stream>>>(phiK, vT, KVT, Ksum);
  scan_s<<<1040, 256, 0, stream>>>(KVT, ST, Ksum, zpre);
  attn_out<<<1024, 256, 0, stream>>>(phiQ, phiK, vT, ST, zpre, y);

  gemm256g<false, float><<<256, 512, 0, stream>>>(y, wob, out, 16384, 1024);
}

// Round 11
// 229.631 us; speedup vs baseline: 2.8074x; 2.8074x over previous
//
#include <hip/hip_runtime.h>

// ---------------------------------------------------------------------------
// CausalLinearAttention (B=4, T=4096, D=1024, H=16, dk=dv=64, CHUNK=64)
// Round 11: revert to R9 best-known (233 us) + single merged cvt launch.
// Ledger: QKV fusion rejected twice (R4, R10: 10-15x write amplification from
// mixed-epilogue L2 thrash). GEMM = 256^2, 2-barrier/K-tile, 16x16x32 MFMA,
// XOR-swizzle, counted vmcnt (R8 A/B winner). transpose64 fused into kv (R9).
// ---------------------------------------------------------------------------

typedef unsigned short u16;
typedef float  f32x4 __attribute__((ext_vector_type(4)));
typedef short  b16x8 __attribute__((ext_vector_type(8)));
typedef u16    u16x4 __attribute__((ext_vector_type(4)));
typedef u16    u16x8 __attribute__((ext_vector_type(8)));

#define DEVINL __device__ __forceinline__

DEVINL u16 f2b(float f) {           // f32 -> bf16 RNE
  unsigned u = __float_as_uint(f);
  return (u16)((u + 0x7fffu + ((u >> 16) & 1u)) >> 16);
}
DEVINL float b2f(u16 s) { return __uint_as_float(((unsigned)s) << 16); }

DEVINL f32x4 mfma16(b16x8 a, b16x8 b, f32x4 c) {
  return __builtin_amdgcn_mfma_f32_16x16x32_bf16(a, b, c, 0, 0, 0);
}

DEVINL float phi_elu1(float v) { return v > 0.f ? v + 1.f : __expf(v); }

// ------------------------------------------------ merged cvt f32->bf16 launch
// blocks [0,2048): x (2,097,152 chunks of 8).  blocks [2048,2560): 128 blocks
// per weight (4 x 131,072 chunks).  Grid-stride within each region.
__global__ void cvt_all(const float* __restrict__ x,
                        const float* __restrict__ Wq, const float* __restrict__ Wk,
                        const float* __restrict__ Wv, const float* __restrict__ Wo,
                        u16* __restrict__ xb, u16* __restrict__ wqb,
                        u16* __restrict__ wkb, u16* __restrict__ wvb,
                        u16* __restrict__ wob) {
  const float* in;
  u16* out;
  int blk0, nblk, n8;
  const int b = blockIdx.x;
  if (b < 2048) {
    in = x; out = xb; blk0 = b; nblk = 2048; n8 = 2097152;
  } else {
    const int w = (b - 2048) >> 7;
    blk0 = (b - 2048) & 127; nblk = 128; n8 = 131072;
    switch (w) {
      case 0: in = Wq; out = wqb; break;
      case 1: in = Wk; out = wkb; break;
      case 2: in = Wv; out = wvb; break;
      default: in = Wo; out = wob; break;
    }
  }
  const int stride = nblk * 256;
  for (int i = blk0 * 256 + threadIdx.x; i < n8; i += stride) {
    const float* p = in + (size_t)i * 8;
    f32x4 a = *(const f32x4*)p;
    f32x4 c = *(const f32x4*)(p + 4);
    u16x8 o;
    o[0] = f2b(a[0]); o[1] = f2b(a[1]); o[2] = f2b(a[2]); o[3] = f2b(a[3]);
    o[4] = f2b(c[0]); o[5] = f2b(c[1]); o[6] = f2b(c[2]); o[7] = f2b(c[3]);
    *(u16x8*)(out + (size_t)i * 8) = o;
  }
}

#define STAGE(tt, h)                                                            \
  do {                                                                          \
    const u16* s_ = ((h) < 2 ? sA : sB) + (size_t)(((h) & 1) * 128) * 1024 +    \
                    (size_t)(tt) * 64;                                          \
    char* d_ = ldsStage + (((tt) & 1) << 16) + ((h) < 2 ? 0 : 32768) +          \
               (((h) & 1) << 14);                                               \
    __builtin_amdgcn_global_load_lds(                                           \
        (const __attribute__((address_space(1))) void*)(s_),                    \
        (__attribute__((address_space(3))) void*)(d_), 16, 0, 0);               \
    __builtin_amdgcn_global_load_lds(                                           \
        (const __attribute__((address_space(1))) void*)(s_ + 64 * 1024),        \
        (__attribute__((address_space(3))) void*)(d_ + 8192), 16, 0, 0);        \
  } while (0)

#define BAR_SB()                                                                \
  do {                                                                          \
    __builtin_amdgcn_s_barrier();                                               \
    __builtin_amdgcn_sched_barrier(0);                                          \
  } while (0)

// -------------------------------------- 256^2 GEMM, 2 barriers per K-tile
// phase A (ks0): {BAR; read a0,a1,b0; stage A(t+1) h0+h1; 32 MFMA}
// phase B (ks1): {BAR; read a0,a1,b1; stage B(t+2) h0+h1; 32 MFMA}
// Counted vmcnt(4) at tile end; vmcnt(0) only for the t>=14 drain.
template <bool PHI, typename OT>
__global__ __launch_bounds__(512, 2) void gemm256g(const u16* __restrict__ A,
                                                   const u16* __restrict__ B,
                                                   OT* __restrict__ C, int M, int N) {
  __shared__ char lds[131072];
  const int tid = threadIdx.x, wid = tid >> 6, l = tid & 63;
  const int l15 = l & 15, lg = l >> 4;
  const int wr = wid >> 2, wc = wid & 3;
  const int ntn = N >> 8;
  const int nwg = gridDim.x, bid = blockIdx.x;
  const int cpx = nwg >> 3;
  const int sb = (bid & 7) * cpx + (bid >> 3);      // XCD swizzle (nwg%8==0)
  const int tm = sb / ntn, tn = sb - tm * ntn;
  const int colX0 = (lg * 16) ^ ((l15 & 7) << 4);
  const int colX1 = (64 + lg * 16) ^ ((l15 & 7) << 4);
  char* ldsA = lds + wr * 16384 + l15 * 128;
  char* ldsB = lds + 32768 + (wc >> 1) * 16384 + ((wc & 1) * 64 + l15) * 128;
  const int srow = tid >> 3;
  const int scol = ((((tid & 7) * 16) ^ ((srow & 7) << 4)) >> 1);
  const u16* sA = A + (size_t)(tm * 256 + srow) * 1024 + scol;
  const u16* sB = B + (size_t)(tn * 256 + srow) * 1024 + scol;
  char* ldsStage = lds + wid * 1024;

  f32x4 acc[8][4];
#pragma unroll
  for (int i = 0; i < 8; i++)
#pragma unroll
    for (int j = 0; j < 4; j++) acc[i][j] = f32x4{0.f, 0.f, 0.f, 0.f};

  STAGE(0, 0); STAGE(0, 1); STAGE(0, 2); STAGE(0, 3);
  STAGE(1, 2); STAGE(1, 3);
  asm volatile("s_waitcnt vmcnt(4)" ::: "memory");

  b16x8 a0[4], a1[4], b0[4], b1[4];
  for (int t = 0; t < 16; ++t) {
    const int cb = (t & 1) << 16;
    // ---- phase A (ks0)
    BAR_SB();
#pragma unroll
    for (int fm = 0; fm < 4; fm++) {
      a0[fm] = *(const b16x8*)(ldsA + cb + fm * 2048 + colX0);
      a1[fm] = *(const b16x8*)(ldsA + cb + (4 + fm) * 2048 + colX0);
    }
#pragma unroll
    for (int fn = 0; fn < 4; fn++) b0[fn] = *(const b16x8*)(ldsB + cb + fn * 2048 + colX0);
    if (t < 15) { STAGE(t + 1, 0); STAGE(t + 1, 1); }
    __builtin_amdgcn_s_setprio(1);
#pragma unroll
    for (int fm = 0; fm < 4; fm++)
#pragma unroll
      for (int fn = 0; fn < 4; fn++) {
        acc[fm][fn] = mfma16(a0[fm], b0[fn], acc[fm][fn]);
        acc[4 + fm][fn] = mfma16(a1[fm], b0[fn], acc[4 + fm][fn]);
      }
    __builtin_amdgcn_s_setprio(0);
    // ---- phase B (ks1)
    BAR_SB();
#pragma unroll
    for (int fm = 0; fm < 4; fm++) {
      a0[fm] = *(const b16x8*)(ldsA + cb + fm * 2048 + colX1);
      a1[fm] = *(const b16x8*)(ldsA + cb + (4 + fm) * 2048 + colX1);
    }
#pragma unroll
    for (int fn = 0; fn < 4; fn++) b1[fn] = *(const b16x8*)(ldsB + cb + fn * 2048 + colX1);
    if (t < 14) { STAGE(t + 2, 2); STAGE(t + 2, 3); }
    __builtin_amdgcn_s_setprio(1);
#pragma unroll
    for (int fm = 0; fm < 4; fm++)
#pragma unroll
      for (int fn = 0; fn < 4; fn++) {
        acc[fm][fn] = mfma16(a0[fm], b1[fn], acc[fm][fn]);
        acc[4 + fm][fn] = mfma16(a1[fm], b1[fn], acc[4 + fm][fn]);
      }
    __builtin_amdgcn_s_setprio(0);
    if (t < 14) asm volatile("s_waitcnt vmcnt(4)" ::: "memory");
    else        asm volatile("s_waitcnt vmcnt(0)" ::: "memory");
  }

#pragma unroll
  for (int fm = 0; fm < 8; ++fm)
#pragma unroll
    for (int fn = 0; fn < 4; ++fn)
#pragma unroll
      for (int r = 0; r < 4; ++r) {
        size_t grow = (size_t)tm * 256 + wr * 128 + fm * 16 + lg * 4 + r;
        size_t gcol = (size_t)tn * 256 + wc * 64 + fn * 16 + l15;
        float v = acc[fm][fn][r];
        if (PHI) v = phi_elu1(v);
        OT* p = C + grow * (size_t)N + gcol;
        if constexpr (sizeof(OT) == 2) *p = (OT)f2b(v);
        else                           *p = (OT)v;
      }
}

// ------------------- per-chunk KV^T (=v^T k) and Ksum, fused phiK transpose
__global__ __launch_bounds__(256, 2) void kv_kernel(const u16* __restrict__ phiK,
                                                    const u16* __restrict__ vT,
                                                    u16* __restrict__ KVT,
                                                    float* __restrict__ Ksum) {
  __shared__ u16 tile[4][64][68];                   // per-wave, +4 pad
  const int tid = threadIdx.x, wid = tid >> 6, l = tid & 63, l15 = l & 15, lg = l >> 4;
  const int bid = blockIdx.x, hg = bid & 3, bn = bid >> 2, n = bn & 63, b = bn >> 6;
  const int h = hg * 4 + wid;
  const size_t row0 = (size_t)b * 4096 + n * 64;
  const int dcol = h * 64;
  const size_t cb = (size_t)b * 4096 + n * 64 + lg * 8;

  b16x8 af[4][2];
#pragma unroll
  for (int fm = 0; fm < 4; fm++)
#pragma unroll
    for (int ks = 0; ks < 2; ks++)
      af[fm][ks] = *(const b16x8*)(vT + (size_t)(h * 64 + fm * 16 + l15) * 16384 + cb + ks * 32);

  u16 (*tw)[68] = tile[wid];
#pragma unroll
  for (int i = 0; i < 8; i++) {
    int tok = i * 8 + (l >> 3);
    int c8 = (l & 7) * 8;
    u16x8 v = *(const u16x8*)(phiK + (row0 + tok) * 1024 + dcol + c8);
    *(u16x4*)(&tw[tok][c8]) = u16x4{v[0], v[1], v[2], v[3]};
    *(u16x4*)(&tw[tok][c8 + 4]) = u16x4{v[4], v[5], v[6], v[7]};
  }
  __syncthreads();

  b16x8 bf[4][2];
#pragma unroll
  for (int fn = 0; fn < 4; fn++)
#pragma unroll
    for (int ks = 0; ks < 2; ks++) {
      b16x8 t;
#pragma unroll
      for (int j = 0; j < 8; j++)
        t[j] = (short)tw[lg * 8 + ks * 32 + j][fn * 16 + l15];
      bf[fn][ks] = t;
    }

  f32x4 acc[4][4];
#pragma unroll
  for (int i = 0; i < 4; i++)
#pragma unroll
    for (int j = 0; j < 4; j++) acc[i][j] = f32x4{0.f, 0.f, 0.f, 0.f};
#pragma unroll
  for (int ks = 0; ks < 2; ks++)
#pragma unroll
    for (int fm = 0; fm < 4; fm++)
#pragma unroll
      for (int fn = 0; fn < 4; fn++) acc[fm][fn] = mfma16(af[fm][ks], bf[fn][ks], acc[fm][fn]);

  float ksum[4] = {0.f, 0.f, 0.f, 0.f};
#pragma unroll
  for (int fn = 0; fn < 4; fn++) {
#pragma unroll
    for (int ks = 0; ks < 2; ks++)
#pragma unroll
      for (int j = 0; j < 8; j++) ksum[fn] += b2f((u16)bf[fn][ks][j]);
    ksum[fn] += __shfl_xor(ksum[fn], 16);
    ksum[fn] += __shfl_xor(ksum[fn], 32);
  }
  const size_t ob = (size_t)(b * 16 + h) * 64 + n;
  if (l < 16) {
#pragma unroll
    for (int fn = 0; fn < 4; fn++) Ksum[ob * 64 + fn * 16 + l15] = ksum[fn];
  }
#pragma unroll
  for (int fm = 0; fm < 4; fm++)
#pragma unroll
    for (int fn = 0; fn < 4; fn++)
#pragma unroll
      for (int r = 0; r < 4; r++)
        KVT[ob * 4096 + (size_t)(fm * 16 + lg * 4 + r) * 64 + fn * 16 + l15] =
            f2b(acc[fm][fn][r]);
}

// ----------------------------- exclusive prefix scans (S and z in one launch)
__global__ __launch_bounds__(256) void scan_s(const u16* __restrict__ KVT,
                                              u16* __restrict__ ST,
                                              const float* __restrict__ Ksum,
                                              float* __restrict__ zpre) {
  if (blockIdx.x >= 1024) {
    const int gi = (blockIdx.x - 1024) * 256 + threadIdx.x;
    const size_t bh = gi >> 6;
    const int dk = gi & 63;
    float acc = 0.f;
    for (int n = 0; n < 64; n++) {
      size_t idx = (bh * 64 + n) * 64 + dk;
      zpre[idx] = acc;
      acc += Ksum[idx];
    }
    return;
  }
  const size_t base = (size_t)(blockIdx.x >> 4) * 64 * 4096 +
                      (blockIdx.x & 15) * 256 + threadIdx.x;
  float acc = 0.f;
  float v[4], w[4];
#pragma unroll
  for (int i = 0; i < 4; i++) v[i] = b2f(KVT[base + (size_t)i * 4096]);
  for (int n = 0; n < 64; n += 4) {
    if (n < 60) {
#pragma unroll
      for (int i = 0; i < 4; i++) w[i] = b2f(KVT[base + (size_t)(n + 4 + i) * 4096]);
    } else {
#pragma unroll
      for (int i = 0; i < 4; i++) w[i] = 0.f;
    }
#pragma unroll
    for (int i = 0; i < 4; i++) {
      ST[base + (size_t)(n + i) * 4096] = f2b(acc);
      acc += v[i];
    }
#pragma unroll
    for (int i = 0; i < 4; i++) v[i] = w[i];
  }
}

// -------------------------------------------------------- fused chunk attention
__global__ __launch_bounds__(256, 2) void attn_out(const u16* __restrict__ phiQ,
                                                   const u16* __restrict__ phiK,
                                                   const u16* __restrict__ vT,
                                                   const u16* __restrict__ ST,
                                                   const float* __restrict__ zpre,
                                                   u16* __restrict__ Y) {
  __shared__ char lds[4 * 8192 + 4 * 256];
  const int tid = threadIdx.x, wid = tid >> 6, l = tid & 63, l15 = l & 15, lg = l >> 4;
  const int bid = blockIdx.x, hg = bid & 3, bn = bid >> 2, n = bn & 63, b = bn >> 6;
  const int h = hg * 4 + wid;
  const size_t row0 = (size_t)b * 4096 + n * 64;
  const int dcol = h * 64;

  b16x8 qf[4][2];
#pragma unroll
  for (int fi = 0; fi < 4; fi++)
#pragma unroll
    for (int ks = 0; ks < 2; ks++)
      qf[fi][ks] = *(const b16x8*)(phiQ + (row0 + fi * 16 + l15) * 1024 + dcol + lg * 8 + ks * 32);

  f32x4 accT[4][4];
#pragma unroll
  for (int i = 0; i < 4; i++)
#pragma unroll
    for (int j = 0; j < 4; j++) accT[i][j] = f32x4{0.f, 0.f, 0.f, 0.f};
  {
    b16x8 kf[4][2];
#pragma unroll
    for (int fj = 0; fj < 4; fj++)
#pragma unroll
      for (int ks = 0; ks < 2; ks++)
        kf[fj][ks] = *(const b16x8*)(phiK + (row0 + fj * 16 + l15) * 1024 + dcol + lg * 8 + ks * 32);
#pragma unroll
    for (int ks = 0; ks < 2; ks++)
#pragma unroll
      for (int fj = 0; fj < 4; fj++)
#pragma unroll
        for (int fi = 0; fi < 4; fi++)
          accT[fj][fi] = mfma16(kf[fj][ks], qf[fi][ks], accT[fj][fi]);
  }

  const size_t zb = ((size_t)(b * 16 + h) * 64 + n) * 64;
  float zi[4] = {0.f, 0.f, 0.f, 0.f};
#pragma unroll
  for (int ks = 0; ks < 2; ks++) {
    f32x4 z0 = *(const f32x4*)(zpre + zb + lg * 8 + ks * 32);
    f32x4 z1 = *(const f32x4*)(zpre + zb + lg * 8 + ks * 32 + 4);
#pragma unroll
    for (int fi = 0; fi < 4; fi++)
#pragma unroll
      for (int j = 0; j < 4; j++) {
        zi[fi] += b2f((u16)qf[fi][ks][j])     * z0[j];
        zi[fi] += b2f((u16)qf[fi][ks][j + 4]) * z1[j];
      }
  }

  char* abuf = lds + wid * 8192;
  float zt[4] = {0.f, 0.f, 0.f, 0.f};
#pragma unroll
  for (int fi = 0; fi < 4; fi++) {
    const int i = fi * 16 + l15;
    const int swz = (i & 7) << 4;
#pragma unroll
    for (int fj = 0; fj < 4; fj++) {
      f32x4 v = accT[fj][fi];
#pragma unroll
      for (int r = 0; r < 4; r++) {
        int j = fj * 16 + lg * 4 + r;
        if (j > i) v[r] = 0.f;
        zt[fi] += v[r];
      }
      unsigned w0 = (unsigned)f2b(v[0]) | ((unsigned)f2b(v[1]) << 16);
      unsigned w1 = (unsigned)f2b(v[2]) | ((unsigned)f2b(v[3]) << 16);
      int jb = (fj * 16 + lg * 4) * 2;
      *(unsigned*)(abuf + i * 128 + (jb ^ swz)) = w0;
      *(unsigned*)(abuf + i * 128 + ((jb + 4) ^ swz)) = w1;
    }
  }

  float* dbuf = (float*)(lds + 32768 + wid * 256);
#pragma unroll
  for (int fi = 0; fi < 4; fi++) {
    float z = zi[fi] + zt[fi];
    z += __shfl_xor(z, 16);
    z += __shfl_xor(z, 32);
    float rd = 1.f / fmaxf(z, 1e-6f);
    if (l < 16) dbuf[fi * 16 + l15] = rd;
  }
  __syncthreads();

  b16x8 stf[4][2], vf[4][2];
  const size_t stb = ((size_t)(b * 16 + h) * 64 + n) * 4096;
#pragma unroll
  for (int fn = 0; fn < 4; fn++)
#pragma unroll
    for (int ks = 0; ks < 2; ks++) {
      stf[fn][ks] = *(const b16x8*)(ST + stb + (size_t)(fn * 16 + l15) * 64 + lg * 8 + ks * 32);
      vf[fn][ks]  = *(const b16x8*)(vT + (size_t)(dcol + fn * 16 + l15) * 16384 +
                                    (size_t)b * 4096 + n * 64 + lg * 8 + ks * 32);
    }
  f32x4 acc[4][4];
#pragma unroll
  for (int i = 0; i < 4; i++)
#pragma unroll
    for (int j = 0; j < 4; j++) acc[i][j] = f32x4{0.f, 0.f, 0.f, 0.f};
#pragma unroll
  for (int ks = 0; ks < 2; ks++)
#pragma unroll
    for (int fm = 0; fm < 4; fm++)
#pragma unroll
      for (int fn = 0; fn < 4; fn++) acc[fm][fn] = mfma16(qf[fm][ks], stf[fn][ks], acc[fm][fn]);
#pragma unroll
  for (int fm = 0; fm < 4; fm++) {
    const int i = fm * 16 + l15;
    const int swz = (i & 7) << 4;
#pragma unroll
    for (int ks = 0; ks < 2; ks++) {
      b16x8 af = *(const b16x8*)(abuf + i * 128 + ((ks * 64 + lg * 16) ^ swz));
#pragma unroll
      for (int fn = 0; fn < 4; fn++) acc[fm][fn] = mfma16(af, vf[fn][ks], acc[fm][fn]);
    }
  }

#pragma unroll
  for (int fm = 0; fm < 4; fm++)
#pragma unroll
    for (int r = 0; r < 4; r++) {
      float rd = dbuf[fm * 16 + lg * 4 + r];
#pragma unroll
      for (int fn = 0; fn < 4; fn++)
        Y[(row0 + fm * 16 + lg * 4 + r) * 1024 + dcol + fn * 16 + l15] =
            f2b(acc[fm][fn][r] * rd);
    }
}

// ---------------------------------------------------------------------------
extern "C" void kernel_launch(void* const* d_in, const int* in_sizes, int n_in,
                              void* d_out, int out_size, void* d_ws, size_t ws_size,
                              hipStream_t stream) {
  const float* x  = (const float*)d_in[0];
  const float* Wq = (const float*)d_in[1];
  const float* Wk = (const float*)d_in[2];
  const float* Wv = (const float*)d_in[3];
  const float* Wo = (const float*)d_in[4];
  float* out = (float*)d_out;

  char* ws = (char*)d_ws;
  size_t off = 0;
  auto alloc = [&](size_t bytes) -> char* {
    char* p = ws + off;
    off += (bytes + 255) & ~(size_t)255;
    return p;
  };
  u16*   xb   = (u16*)alloc(33554432);   // x bf16 (reused as y later)
  u16*   wqb  = (u16*)alloc(2097152);
  u16*   wkb  = (u16*)alloc(2097152);
  u16*   wvb  = (u16*)alloc(2097152);
  u16*   wob  = (u16*)alloc(2097152);
  u16*   phiQ = (u16*)alloc(33554432);
  u16*   phiK = (u16*)alloc(33554432);
  u16*   vT   = (u16*)alloc(33554432);
  u16*   KVT  = (u16*)alloc(33554432);
  float* Ksum = (float*)alloc(1048576);
  u16*   ST   = (u16*)alloc(33554432);
  float* zpre = (float*)alloc(1048576);
  u16*   y    = xb;   // alias: xb dead after the V GEMM

  cvt_all<<<2560, 256, 0, stream>>>(x, Wq, Wk, Wv, Wo, xb, wqb, wkb, wvb, wob);

  gemm256g<true, u16><<<256, 512, 0, stream>>>(xb, wqb, phiQ, 16384, 1024);
  gemm256g<true, u16><<<256, 512, 0, stream>>>(xb, wkb, phiK, 16384, 1024);
  gemm256g<false, u16><<<256, 512, 0, stream>>>(wvb, xb, vT, 1024, 16384);

  kv_kernel<<<1024, 256, 0, stream>>>(phiK, vT, KVT, Ksum);
  scan_s<<<1040, 256, 0, stream>>>(KVT, ST, Ksum, zpre);
  attn_out<<<1024, 256, 0, stream>>>(phiQ, phiK, vT, ST, zpre, y);

  gemm256g<false, float><<<256, 512, 0, stream>>>(y, wob, out, 16384, 1024);
}

// Round 12
// 223.564 us; speedup vs baseline: 2.8836x; 1.0271x over previous
//
#include <hip/hip_runtime.h>

// ---------------------------------------------------------------------------
// CausalLinearAttention (B=4, T=4096, D=1024, H=16, dk=dv=64, CHUNK=64)
// Round 12: (a) A/B barrier density once more: Q = gemm256h (1 barrier/K-tile,
// all 24 frags read up front, same counted-vmcnt ledger) vs K = gemm256g
// (2-barrier, R8 winner); V/out = gemm256g. (b) scan_s 2-elem vectorized.
// Ledger: QKV fusion rejected (R4/R10); 32x32 rejected (R6); 8-phase null at
// K=1024 (R2); GEMM ~39% of MFMA floor, barrier-lever near exhaustion.
// ---------------------------------------------------------------------------

typedef unsigned short u16;
typedef float  f32x4 __attribute__((ext_vector_type(4)));
typedef short  b16x8 __attribute__((ext_vector_type(8)));
typedef u16    u16x4 __attribute__((ext_vector_type(4)));
typedef u16    u16x8 __attribute__((ext_vector_type(8)));

#define DEVINL __device__ __forceinline__

DEVINL u16 f2b(float f) {           // f32 -> bf16 RNE
  unsigned u = __float_as_uint(f);
  return (u16)((u + 0x7fffu + ((u >> 16) & 1u)) >> 16);
}
DEVINL float b2f(u16 s) { return __uint_as_float(((unsigned)s) << 16); }

DEVINL f32x4 mfma16(b16x8 a, b16x8 b, f32x4 c) {
  return __builtin_amdgcn_mfma_f32_16x16x32_bf16(a, b, c, 0, 0, 0);
}

DEVINL float phi_elu1(float v) { return v > 0.f ? v + 1.f : __expf(v); }

// ------------------------------------------------ merged cvt f32->bf16 launch
__global__ void cvt_all(const float* __restrict__ x,
                        const float* __restrict__ Wq, const float* __restrict__ Wk,
                        const float* __restrict__ Wv, const float* __restrict__ Wo,
                        u16* __restrict__ xb, u16* __restrict__ wqb,
                        u16* __restrict__ wkb, u16* __restrict__ wvb,
                        u16* __restrict__ wob) {
  const float* in;
  u16* out;
  int blk0, nblk, n8;
  const int b = blockIdx.x;
  if (b < 2048) {
    in = x; out = xb; blk0 = b; nblk = 2048; n8 = 2097152;
  } else {
    const int w = (b - 2048) >> 7;
    blk0 = (b - 2048) & 127; nblk = 128; n8 = 131072;
    switch (w) {
      case 0: in = Wq; out = wqb; break;
      case 1: in = Wk; out = wkb; break;
      case 2: in = Wv; out = wvb; break;
      default: in = Wo; out = wob; break;
    }
  }
  const int stride = nblk * 256;
  for (int i = blk0 * 256 + threadIdx.x; i < n8; i += stride) {
    const float* p = in + (size_t)i * 8;
    f32x4 a = *(const f32x4*)p;
    f32x4 c = *(const f32x4*)(p + 4);
    u16x8 o;
    o[0] = f2b(a[0]); o[1] = f2b(a[1]); o[2] = f2b(a[2]); o[3] = f2b(a[3]);
    o[4] = f2b(c[0]); o[5] = f2b(c[1]); o[6] = f2b(c[2]); o[7] = f2b(c[3]);
    *(u16x8*)(out + (size_t)i * 8) = o;
  }
}

#define GEMM_SETUP                                                              \
  __shared__ char lds[131072];                                                  \
  const int tid = threadIdx.x, wid = tid >> 6, l = tid & 63;                    \
  const int l15 = l & 15, lg = l >> 4;                                          \
  const int wr = wid >> 2, wc = wid & 3;                                        \
  const int ntn = N >> 8;                                                       \
  const int nwg = gridDim.x, bid = blockIdx.x;                                  \
  const int cpx = nwg >> 3;                                                     \
  const int sb = (bid & 7) * cpx + (bid >> 3);                                  \
  const int tm = sb / ntn, tn = sb - tm * ntn;                                  \
  const int colX0 = (lg * 16) ^ ((l15 & 7) << 4);                               \
  const int colX1 = (64 + lg * 16) ^ ((l15 & 7) << 4);                          \
  char* ldsA = lds + wr * 16384 + l15 * 128;                                    \
  char* ldsB = lds + 32768 + (wc >> 1) * 16384 + ((wc & 1) * 64 + l15) * 128;   \
  const int srow = tid >> 3;                                                    \
  const int scol = ((((tid & 7) * 16) ^ ((srow & 7) << 4)) >> 1);               \
  const u16* sA = A + (size_t)(tm * 256 + srow) * 1024 + scol;                  \
  const u16* sB = B + (size_t)(tn * 256 + srow) * 1024 + scol;                  \
  char* ldsStage = lds + wid * 1024;

#define STAGE(tt, h)                                                            \
  do {                                                                          \
    const u16* s_ = ((h) < 2 ? sA : sB) + (size_t)(((h) & 1) * 128) * 1024 +    \
                    (size_t)(tt) * 64;                                          \
    char* d_ = ldsStage + (((tt) & 1) << 16) + ((h) < 2 ? 0 : 32768) +          \
               (((h) & 1) << 14);                                               \
    __builtin_amdgcn_global_load_lds(                                           \
        (const __attribute__((address_space(1))) void*)(s_),                    \
        (__attribute__((address_space(3))) void*)(d_), 16, 0, 0);               \
    __builtin_amdgcn_global_load_lds(                                           \
        (const __attribute__((address_space(1))) void*)(s_ + 64 * 1024),        \
        (__attribute__((address_space(3))) void*)(d_ + 8192), 16, 0, 0);        \
  } while (0)

#define BAR_SB()                                                                \
  do {                                                                          \
    __builtin_amdgcn_s_barrier();                                               \
    __builtin_amdgcn_sched_barrier(0);                                          \
  } while (0)

#define GEMM_EPILOGUE                                                           \
  _Pragma("unroll") for (int fm = 0; fm < 8; ++fm)                              \
    _Pragma("unroll") for (int fn = 0; fn < 4; ++fn)                            \
      _Pragma("unroll") for (int r = 0; r < 4; ++r) {                           \
        size_t grow = (size_t)tm * 256 + wr * 128 + fm * 16 + lg * 4 + r;       \
        size_t gcol = (size_t)tn * 256 + wc * 64 + fn * 16 + l15;               \
        float v = acc[fm][fn][r];                                               \
        if (PHI) v = phi_elu1(v);                                               \
        OT* p = C + grow * (size_t)N + gcol;                                    \
        if constexpr (sizeof(OT) == 2) *p = (OT)f2b(v);                         \
        else                           *p = (OT)v;                              \
      }

// ------------------------------ VARIANT A: 2 barriers per K-tile (R8 winner)
template <bool PHI, typename OT>
__global__ __launch_bounds__(512, 2) void gemm256g(const u16* __restrict__ A,
                                                   const u16* __restrict__ B,
                                                   OT* __restrict__ C, int M, int N) {
  GEMM_SETUP

  f32x4 acc[8][4];
#pragma unroll
  for (int i = 0; i < 8; i++)
#pragma unroll
    for (int j = 0; j < 4; j++) acc[i][j] = f32x4{0.f, 0.f, 0.f, 0.f};

  STAGE(0, 0); STAGE(0, 1); STAGE(0, 2); STAGE(0, 3);
  STAGE(1, 2); STAGE(1, 3);
  asm volatile("s_waitcnt vmcnt(4)" ::: "memory");

  b16x8 a0[4], a1[4], b0[4], b1[4];
  for (int t = 0; t < 16; ++t) {
    const int cb = (t & 1) << 16;
    // ---- phase A (ks0)
    BAR_SB();
#pragma unroll
    for (int fm = 0; fm < 4; fm++) {
      a0[fm] = *(const b16x8*)(ldsA + cb + fm * 2048 + colX0);
      a1[fm] = *(const b16x8*)(ldsA + cb + (4 + fm) * 2048 + colX0);
    }
#pragma unroll
    for (int fn = 0; fn < 4; fn++) b0[fn] = *(const b16x8*)(ldsB + cb + fn * 2048 + colX0);
    if (t < 15) { STAGE(t + 1, 0); STAGE(t + 1, 1); }
    __builtin_amdgcn_s_setprio(1);
#pragma unroll
    for (int fm = 0; fm < 4; fm++)
#pragma unroll
      for (int fn = 0; fn < 4; fn++) {
        acc[fm][fn] = mfma16(a0[fm], b0[fn], acc[fm][fn]);
        acc[4 + fm][fn] = mfma16(a1[fm], b0[fn], acc[4 + fm][fn]);
      }
    __builtin_amdgcn_s_setprio(0);
    // ---- phase B (ks1)
    BAR_SB();
#pragma unroll
    for (int fm = 0; fm < 4; fm++) {
      a0[fm] = *(const b16x8*)(ldsA + cb + fm * 2048 + colX1);
      a1[fm] = *(const b16x8*)(ldsA + cb + (4 + fm) * 2048 + colX1);
    }
#pragma unroll
    for (int fn = 0; fn < 4; fn++) b1[fn] = *(const b16x8*)(ldsB + cb + fn * 2048 + colX1);
    if (t < 14) { STAGE(t + 2, 2); STAGE(t + 2, 3); }
    __builtin_amdgcn_s_setprio(1);
#pragma unroll
    for (int fm = 0; fm < 4; fm++)
#pragma unroll
      for (int fn = 0; fn < 4; fn++) {
        acc[fm][fn] = mfma16(a0[fm], b1[fn], acc[fm][fn]);
        acc[4 + fm][fn] = mfma16(a1[fm], b1[fn], acc[4 + fm][fn]);
      }
    __builtin_amdgcn_s_setprio(0);
    if (t < 14) asm volatile("s_waitcnt vmcnt(4)" ::: "memory");
    else        asm volatile("s_waitcnt vmcnt(0)" ::: "memory");
  }

  GEMM_EPILOGUE
}

// ------------------------------ VARIANT B: 1 barrier per K-tile
// {BAR; read ALL 24 frags of tile t; stage A(t+1)h0+h1, B(t+2)h0+h1;
//  setprio; 64 MFMA; setprio; counted vmcnt}.  Identical vmcnt ledger:
// at tile end outstanding = B(t+1)4 + A(t+1)4 + B(t+2)4; vmcnt(4) drains
// B(t+1)+A(t+1), leaves B(t+2) in flight.
template <bool PHI, typename OT>
__global__ __launch_bounds__(512, 2) void gemm256h(const u16* __restrict__ A,
                                                   const u16* __restrict__ B,
                                                   OT* __restrict__ C, int M, int N) {
  GEMM_SETUP

  f32x4 acc[8][4];
#pragma unroll
  for (int i = 0; i < 8; i++)
#pragma unroll
    for (int j = 0; j < 4; j++) acc[i][j] = f32x4{0.f, 0.f, 0.f, 0.f};

  STAGE(0, 0); STAGE(0, 1); STAGE(0, 2); STAGE(0, 3);
  STAGE(1, 2); STAGE(1, 3);
  asm volatile("s_waitcnt vmcnt(4)" ::: "memory");

  b16x8 a0[4], a1[4], a2[4], a3[4], b0[4], b1[4];
  for (int t = 0; t < 16; ++t) {
    const int cb = (t & 1) << 16;
    BAR_SB();
#pragma unroll
    for (int fm = 0; fm < 4; fm++) {
      a0[fm] = *(const b16x8*)(ldsA + cb + fm * 2048 + colX0);
      a1[fm] = *(const b16x8*)(ldsA + cb + (4 + fm) * 2048 + colX0);
      a2[fm] = *(const b16x8*)(ldsA + cb + fm * 2048 + colX1);
      a3[fm] = *(const b16x8*)(ldsA + cb + (4 + fm) * 2048 + colX1);
    }
#pragma unroll
    for (int fn = 0; fn < 4; fn++) {
      b0[fn] = *(const b16x8*)(ldsB + cb + fn * 2048 + colX0);
      b1[fn] = *(const b16x8*)(ldsB + cb + fn * 2048 + colX1);
    }
    if (t < 15) { STAGE(t + 1, 0); STAGE(t + 1, 1); }
    if (t < 14) { STAGE(t + 2, 2); STAGE(t + 2, 3); }
    __builtin_amdgcn_s_setprio(1);
#pragma unroll
    for (int fm = 0; fm < 4; fm++)
#pragma unroll
      for (int fn = 0; fn < 4; fn++) {
        acc[fm][fn] = mfma16(a0[fm], b0[fn], acc[fm][fn]);
        acc[4 + fm][fn] = mfma16(a1[fm], b0[fn], acc[4 + fm][fn]);
      }
#pragma unroll
    for (int fm = 0; fm < 4; fm++)
#pragma unroll
      for (int fn = 0; fn < 4; fn++) {
        acc[fm][fn] = mfma16(a2[fm], b1[fn], acc[fm][fn]);
        acc[4 + fm][fn] = mfma16(a3[fm], b1[fn], acc[4 + fm][fn]);
      }
    __builtin_amdgcn_s_setprio(0);
    if (t < 14) asm volatile("s_waitcnt vmcnt(4)" ::: "memory");
    else        asm volatile("s_waitcnt vmcnt(0)" ::: "memory");
  }

  GEMM_EPILOGUE
}

// ------------------- per-chunk KV^T (=v^T k) and Ksum, fused phiK transpose
__global__ __launch_bounds__(256, 2) void kv_kernel(const u16* __restrict__ phiK,
                                                    const u16* __restrict__ vT,
                                                    u16* __restrict__ KVT,
                                                    float* __restrict__ Ksum) {
  __shared__ u16 tile[4][64][68];                   // per-wave, +4 pad
  const int tid = threadIdx.x, wid = tid >> 6, l = tid & 63, l15 = l & 15, lg = l >> 4;
  const int bid = blockIdx.x, hg = bid & 3, bn = bid >> 2, n = bn & 63, b = bn >> 6;
  const int h = hg * 4 + wid;
  const size_t row0 = (size_t)b * 4096 + n * 64;
  const int dcol = h * 64;
  const size_t cb = (size_t)b * 4096 + n * 64 + lg * 8;

  b16x8 af[4][2];
#pragma unroll
  for (int fm = 0; fm < 4; fm++)
#pragma unroll
    for (int ks = 0; ks < 2; ks++)
      af[fm][ks] = *(const b16x8*)(vT + (size_t)(h * 64 + fm * 16 + l15) * 16384 + cb + ks * 32);

  u16 (*tw)[68] = tile[wid];
#pragma unroll
  for (int i = 0; i < 8; i++) {
    int tok = i * 8 + (l >> 3);
    int c8 = (l & 7) * 8;
    u16x8 v = *(const u16x8*)(phiK + (row0 + tok) * 1024 + dcol + c8);
    *(u16x4*)(&tw[tok][c8]) = u16x4{v[0], v[1], v[2], v[3]};
    *(u16x4*)(&tw[tok][c8 + 4]) = u16x4{v[4], v[5], v[6], v[7]};
  }
  __syncthreads();

  b16x8 bf[4][2];
#pragma unroll
  for (int fn = 0; fn < 4; fn++)
#pragma unroll
    for (int ks = 0; ks < 2; ks++) {
      b16x8 t;
#pragma unroll
      for (int j = 0; j < 8; j++)
        t[j] = (short)tw[lg * 8 + ks * 32 + j][fn * 16 + l15];
      bf[fn][ks] = t;
    }

  f32x4 acc[4][4];
#pragma unroll
  for (int i = 0; i < 4; i++)
#pragma unroll
    for (int j = 0; j < 4; j++) acc[i][j] = f32x4{0.f, 0.f, 0.f, 0.f};
#pragma unroll
  for (int ks = 0; ks < 2; ks++)
#pragma unroll
    for (int fm = 0; fm < 4; fm++)
#pragma unroll
      for (int fn = 0; fn < 4; fn++) acc[fm][fn] = mfma16(af[fm][ks], bf[fn][ks], acc[fm][fn]);

  float ksum[4] = {0.f, 0.f, 0.f, 0.f};
#pragma unroll
  for (int fn = 0; fn < 4; fn++) {
#pragma unroll
    for (int ks = 0; ks < 2; ks++)
#pragma unroll
      for (int j = 0; j < 8; j++) ksum[fn] += b2f((u16)bf[fn][ks][j]);
    ksum[fn] += __shfl_xor(ksum[fn], 16);
    ksum[fn] += __shfl_xor(ksum[fn], 32);
  }
  const size_t ob = (size_t)(b * 16 + h) * 64 + n;
  if (l < 16) {
#pragma unroll
    for (int fn = 0; fn < 4; fn++) Ksum[ob * 64 + fn * 16 + l15] = ksum[fn];
  }
#pragma unroll
  for (int fm = 0; fm < 4; fm++)
#pragma unroll
    for (int fn = 0; fn < 4; fn++)
#pragma unroll
      for (int r = 0; r < 4; r++)
        KVT[ob * 4096 + (size_t)(fm * 16 + lg * 4 + r) * 64 + fn * 16 + l15] =
            f2b(acc[fm][fn][r]);
}

// --------------- exclusive prefix scans (S 2-elem vectorized + z, one launch)
// blocks [0,512): ST scan, 2 elems/thread (u32 = 2 bf16), 4-deep prefetch.
// blocks [512,528): zpre scan.
__global__ __launch_bounds__(256) void scan_s(const u16* __restrict__ KVT,
                                              u16* __restrict__ ST,
                                              const float* __restrict__ Ksum,
                                              float* __restrict__ zpre) {
  if (blockIdx.x >= 512) {
    const int gi = (blockIdx.x - 512) * 256 + threadIdx.x;   // (bh, dk)
    const size_t bh = gi >> 6;
    const int dk = gi & 63;
    float acc = 0.f;
    for (int n = 0; n < 64; n++) {
      size_t idx = (bh * 64 + n) * 64 + dk;
      zpre[idx] = acc;
      acc += Ksum[idx];
    }
    return;
  }
  const size_t base2 = (size_t)(blockIdx.x >> 3) * 64 * 2048 +
                       (blockIdx.x & 7) * 256 + threadIdx.x;   // in u32 units
  const unsigned* KV32 = (const unsigned*)KVT;
  unsigned* ST32 = (unsigned*)ST;
  float ac0 = 0.f, ac1 = 0.f;
  unsigned v[4], w[4];
#pragma unroll
  for (int i = 0; i < 4; i++) v[i] = KV32[base2 + (size_t)i * 2048];
  for (int n = 0; n < 64; n += 4) {
    if (n < 60) {
#pragma unroll
      for (int i = 0; i < 4; i++) w[i] = KV32[base2 + (size_t)(n + 4 + i) * 2048];
    } else {
#pragma unroll
      for (int i = 0; i < 4; i++) w[i] = 0u;
    }
#pragma unroll
    for (int i = 0; i < 4; i++) {
      ST32[base2 + (size_t)(n + i) * 2048] =
          (unsigned)f2b(ac0) | ((unsigned)f2b(ac1) << 16);
      ac0 += b2f((u16)(v[i] & 0xffff));
      ac1 += b2f((u16)(v[i] >> 16));
    }
#pragma unroll
    for (int i = 0; i < 4; i++) v[i] = w[i];
  }
}

// -------------------------------------------------------- fused chunk attention
__global__ __launch_bounds__(256, 2) void attn_out(const u16* __restrict__ phiQ,
                                                   const u16* __restrict__ phiK,
                                                   const u16* __restrict__ vT,
                                                   const u16* __restrict__ ST,
                                                   const float* __restrict__ zpre,
                                                   u16* __restrict__ Y) {
  __shared__ char lds[4 * 8192 + 4 * 256];
  const int tid = threadIdx.x, wid = tid >> 6, l = tid & 63, l15 = l & 15, lg = l >> 4;
  const int bid = blockIdx.x, hg = bid & 3, bn = bid >> 2, n = bn & 63, b = bn >> 6;
  const int h = hg * 4 + wid;
  const size_t row0 = (size_t)b * 4096 + n * 64;
  const int dcol = h * 64;

  b16x8 qf[4][2];
#pragma unroll
  for (int fi = 0; fi < 4; fi++)
#pragma unroll
    for (int ks = 0; ks < 2; ks++)
      qf[fi][ks] = *(const b16x8*)(phiQ + (row0 + fi * 16 + l15) * 1024 + dcol + lg * 8 + ks * 32);

  f32x4 accT[4][4];
#pragma unroll
  for (int i = 0; i < 4; i++)
#pragma unroll
    for (int j = 0; j < 4; j++) accT[i][j] = f32x4{0.f, 0.f, 0.f, 0.f};
  {
    b16x8 kf[4][2];
#pragma unroll
    for (int fj = 0; fj < 4; fj++)
#pragma unroll
      for (int ks = 0; ks < 2; ks++)
        kf[fj][ks] = *(const b16x8*)(phiK + (row0 + fj * 16 + l15) * 1024 + dcol + lg * 8 + ks * 32);
#pragma unroll
    for (int ks = 0; ks < 2; ks++)
#pragma unroll
      for (int fj = 0; fj < 4; fj++)
#pragma unroll
        for (int fi = 0; fi < 4; fi++)
          accT[fj][fi] = mfma16(kf[fj][ks], qf[fi][ks], accT[fj][fi]);
  }

  const size_t zb = ((size_t)(b * 16 + h) * 64 + n) * 64;
  float zi[4] = {0.f, 0.f, 0.f, 0.f};
#pragma unroll
  for (int ks = 0; ks < 2; ks++) {
    f32x4 z0 = *(const f32x4*)(zpre + zb + lg * 8 + ks * 32);
    f32x4 z1 = *(const f32x4*)(zpre + zb + lg * 8 + ks * 32 + 4);
#pragma unroll
    for (int fi = 0; fi < 4; fi++)
#pragma unroll
      for (int j = 0; j < 4; j++) {
        zi[fi] += b2f((u16)qf[fi][ks][j])     * z0[j];
        zi[fi] += b2f((u16)qf[fi][ks][j + 4]) * z1[j];
      }
  }

  char* abuf = lds + wid * 8192;
  float zt[4] = {0.f, 0.f, 0.f, 0.f};
#pragma unroll
  for (int fi = 0; fi < 4; fi++) {
    const int i = fi * 16 + l15;
    const int swz = (i & 7) << 4;
#pragma unroll
    for (int fj = 0; fj < 4; fj++) {
      f32x4 v = accT[fj][fi];
#pragma unroll
      for (int r = 0; r < 4; r++) {
        int j = fj * 16 + lg * 4 + r;
        if (j > i) v[r] = 0.f;
        zt[fi] += v[r];
      }
      unsigned w0 = (unsigned)f2b(v[0]) | ((unsigned)f2b(v[1]) << 16);
      unsigned w1 = (unsigned)f2b(v[2]) | ((unsigned)f2b(v[3]) << 16);
      int jb = (fj * 16 + lg * 4) * 2;
      *(unsigned*)(abuf + i * 128 + (jb ^ swz)) = w0;
      *(unsigned*)(abuf + i * 128 + ((jb + 4) ^ swz)) = w1;
    }
  }

  float* dbuf = (float*)(lds + 32768 + wid * 256);
#pragma unroll
  for (int fi = 0; fi < 4; fi++) {
    float z = zi[fi] + zt[fi];
    z += __shfl_xor(z, 16);
    z += __shfl_xor(z, 32);
    float rd = 1.f / fmaxf(z, 1e-6f);
    if (l < 16) dbuf[fi * 16 + l15] = rd;
  }
  __syncthreads();

  b16x8 stf[4][2], vf[4][2];
  const size_t stb = ((size_t)(b * 16 + h) * 64 + n) * 4096;
#pragma unroll
  for (int fn = 0; fn < 4; fn++)
#pragma unroll
    for (int ks = 0; ks < 2; ks++) {
      stf[fn][ks] = *(const b16x8*)(ST + stb + (size_t)(fn * 16 + l15) * 64 + lg * 8 + ks * 32);
      vf[fn][ks]  = *(const b16x8*)(vT + (size_t)(dcol + fn * 16 + l15) * 16384 +
                                    (size_t)b * 4096 + n * 64 + lg * 8 + ks * 32);
    }
  f32x4 acc[4][4];
#pragma unroll
  for (int i = 0; i < 4; i++)
#pragma unroll
    for (int j = 0; j < 4; j++) acc[i][j] = f32x4{0.f, 0.f, 0.f, 0.f};
#pragma unroll
  for (int ks = 0; ks < 2; ks++)
#pragma unroll
    for (int fm = 0; fm < 4; fm++)
#pragma unroll
      for (int fn = 0; fn < 4; fn++) acc[fm][fn] = mfma16(qf[fm][ks], stf[fn][ks], acc[fm][fn]);
#pragma unroll
  for (int fm = 0; fm < 4; fm++) {
    const int i = fm * 16 + l15;
    const int swz = (i & 7) << 4;
#pragma unroll
    for (int ks = 0; ks < 2; ks++) {
      b16x8 af = *(const b16x8*)(abuf + i * 128 + ((ks * 64 + lg * 16) ^ swz));
#pragma unroll
      for (int fn = 0; fn < 4; fn++) acc[fm][fn] = mfma16(af, vf[fn][ks], acc[fm][fn]);
    }
  }

#pragma unroll
  for (int fm = 0; fm < 4; fm++)
#pragma unroll
    for (int r = 0; r < 4; r++) {
      float rd = dbuf[fm * 16 + lg * 4 + r];
#pragma unroll
      for (int fn = 0; fn < 4; fn++)
        Y[(row0 + fm * 16 + lg * 4 + r) * 1024 + dcol + fn * 16 + l15] =
            f2b(acc[fm][fn][r] * rd);
    }
}

// ---------------------------------------------------------------------------
extern "C" void kernel_launch(void* const* d_in, const int* in_sizes, int n_in,
                              void* d_out, int out_size, void* d_ws, size_t ws_size,
                              hipStream_t stream) {
  const float* x  = (const float*)d_in[0];
  const float* Wq = (const float*)d_in[1];
  const float* Wk = (const float*)d_in[2];
  const float* Wv = (const float*)d_in[3];
  const float* Wo = (const float*)d_in[4];
  float* out = (float*)d_out;

  char* ws = (char*)d_ws;
  size_t off = 0;
  auto alloc = [&](size_t bytes) -> char* {
    char* p = ws + off;
    off += (bytes + 255) & ~(size_t)255;
    return p;
  };
  u16*   xb   = (u16*)alloc(33554432);   // x bf16 (reused as y later)
  u16*   wqb  = (u16*)alloc(2097152);
  u16*   wkb  = (u16*)alloc(2097152);
  u16*   wvb  = (u16*)alloc(2097152);
  u16*   wob  = (u16*)alloc(2097152);
  u16*   phiQ = (u16*)alloc(33554432);
  u16*   phiK = (u16*)alloc(33554432);
  u16*   vT   = (u16*)alloc(33554432);
  u16*   KVT  = (u16*)alloc(33554432);
  float* Ksum = (float*)alloc(1048576);
  u16*   ST   = (u16*)alloc(33554432);
  float* zpre = (float*)alloc(1048576);
  u16*   y    = xb;   // alias: xb dead after the V GEMM

  cvt_all<<<2560, 256, 0, stream>>>(x, Wq, Wk, Wv, Wo, xb, wqb, wkb, wvb, wob);

  // A/B: identical shape, 1-barrier vs 2-barrier K-tile schedule
  gemm256h<true, u16><<<256, 512, 0, stream>>>(xb, wqb, phiQ, 16384, 1024);   // 1-bar
  gemm256g<true, u16><<<256, 512, 0, stream>>>(xb, wkb, phiK, 16384, 1024);   // 2-bar
  gemm256g<false, u16><<<256, 512, 0, stream>>>(wvb, xb, vT, 1024, 16384);

  kv_kernel<<<1024, 256, 0, stream>>>(phiK, vT, KVT, Ksum);
  scan_s<<<528, 256, 0, stream>>>(KVT, ST, Ksum, zpre);
  attn_out<<<1024, 256, 0, stream>>>(phiQ, phiK, vT, ST, zpre, y);

  gemm256g<false, float><<<256, 512, 0, stream>>>(y, wob, out, 16384, 1024);
}